// Round 3
// baseline (864.204 us; speedup 1.0000x reference)
//
#include <hip/hip_runtime.h>

#define NEG_SLOPE 0.2f

// leaky_relu(m) = 0.6*m + 0.4*|m|  (exact for slope 0.2)
static __device__ __forceinline__ float lrelu(float m) {
    return fmaf(0.4f, fabsf(m), 0.6f * m);
}

static __device__ __forceinline__ float wsum64(float v) {
#pragma unroll
    for (int off = 32; off >= 1; off >>= 1) v += __shfl_xor(v, off, 64);
    return v;
}
static __device__ __forceinline__ float wsum32(float v) {
#pragma unroll
    for (int off = 16; off >= 1; off >>= 1) v += __shfl_xor(v, off, 64);
    return v;
}
static __device__ __forceinline__ float wmax64(float v) {
#pragma unroll
    for (int off = 32; off >= 1; off >>= 1) v = fmaxf(v, __shfl_xor(v, off, 64));
    return v;
}

// pack two fp32 -> two bf16 (RNE) in one uint
static __device__ __forceinline__ unsigned int bf16pack(float a, float b) {
    unsigned int ua = __float_as_uint(a);
    ua = (ua + 0x7FFFu + ((ua >> 16) & 1u)) >> 16;
    unsigned int ub = __float_as_uint(b);
    ub = (ub + 0x7FFFu + ((ub >> 16) & 1u)) & 0xFFFF0000u;
    return ua | ub;
}
// expand 4 bf16 (uint2) -> float4
static __device__ __forceinline__ float4 bf16x4_to_f4(uint2 u) {
    float4 v;
    v.x = __uint_as_float(u.x << 16);
    v.y = __uint_as_float(u.x & 0xFFFF0000u);
    v.z = __uint_as_float(u.y << 16);
    v.w = __uint_as_float(u.y & 0xFFFF0000u);
    return v;
}

// per-lane partial of leakyrelu(xs + pre) . av over this lane's 4 dims
static __device__ __forceinline__ float ldot4(const float4 xs, const float4 pre,
                                              const float4 av) {
    float q;
    q  = lrelu(xs.x + pre.x) * av.x;
    q += lrelu(xs.y + pre.y) * av.y;
    q += lrelu(xs.z + pre.z) * av.z;
    q += lrelu(xs.w + pre.w) * av.w;
    return q;
}

// ---------- init ----------
__global__ void k_zero_all(int* __restrict__ cntw, int n, int* __restrict__ cnt3,
                           int* __restrict__ gsum) {
    int i = blockIdx.x * blockDim.x + threadIdx.x;
    if (i < n) cntw[i] = 0;
    if (i < 4) cnt3[i] = 0;
    if (i < 32) gsum[i] = 0;
}

// fused: dst histogram + flow-value counts
__global__ void k_edges(const int* __restrict__ ei, const int* __restrict__ ea,
                        int* __restrict__ cnt, int* __restrict__ cnt3, int E) {
    __shared__ int sh3[3];
    if (threadIdx.x < 3) sh3[threadIdx.x] = 0;
    __syncthreads();
    int e = blockIdx.x * blockDim.x + threadIdx.x;
    if (e < E) {
        atomicAdd(&cnt[ei[E + e]], 1);
        int f = ea[2 * e];
        f = f < 0 ? 0 : (f > 2 ? 2 : f);
        atomicAdd(&sh3[f], 1);
    }
    __syncthreads();
    if (threadIdx.x < 3) atomicAdd(&cnt3[threadIdx.x], sh3[threadIdx.x]);
}

// posc = pos_table[MAX_POS] @ pos_W + pos_b is constant for ALL edges
// (clip(where(pos>MP,pos,MP),0,MP) == MP identically). Project 3 flow vectors
// + self-loop mean vector through We1 / We2.
__global__ void k_prep(const float* __restrict__ pos_table, const float* __restrict__ pos_W,
                       const float* __restrict__ pos_b, const float* __restrict__ flow_emb,
                       const float* __restrict__ We1, const float* __restrict__ We2,
                       const int* __restrict__ cnt3,
                       float* __restrict__ eaW1, float* __restrict__ loopW1,
                       float* __restrict__ eaW2, float* __restrict__ loopW2, int E) {
    __shared__ float posc[128];
    __shared__ float lv[128];
    int t = threadIdx.x;
    if (t < 128) {
        const float* row = pos_table + 5120 * 128;
        float a = pos_b[t];
        for (int k = 0; k < 128; ++k) a += row[k] * pos_W[k * 128 + t];
        posc[t] = a;
        float invE = 1.0f / (float)E;
        lv[t] = ((float)cnt3[0] * flow_emb[t] + (float)cnt3[1] * flow_emb[128 + t] +
                 (float)cnt3[2] * flow_emb[256 + t]) * invE + a;
    }
    __syncthreads();
    {   // layer 1 projections, j = 0..255
        int j = t;
        float a0 = 0.f, a1 = 0.f, a2 = 0.f, al = 0.f;
        for (int k = 0; k < 128; ++k) {
            float w = We1[k * 256 + j];
            float pc = posc[k];
            a0 += (flow_emb[k] + pc) * w;
            a1 += (flow_emb[128 + k] + pc) * w;
            a2 += (flow_emb[256 + k] + pc) * w;
            al += lv[k] * w;
        }
        eaW1[j] = a0; eaW1[256 + j] = a1; eaW1[512 + j] = a2; loopW1[j] = al;
    }
    if (t < 32) {  // layer 2 projections
        int j = t;
        float a0 = 0.f, a1 = 0.f, a2 = 0.f, al = 0.f;
        for (int k = 0; k < 128; ++k) {
            float w = We2[k * 32 + j];
            float pc = posc[k];
            a0 += (flow_emb[k] + pc) * w;
            a1 += (flow_emb[128 + k] + pc) * w;
            a2 += (flow_emb[256 + k] + pc) * w;
            al += lv[k] * w;
        }
        eaW2[j] = a0; eaW2[32 + j] = a1; eaW2[64 + j] = a2; loopW2[j] = al;
    }
}

// ---------- CSR-by-dst build ----------
__global__ __launch_bounds__(256) void k_scan_block(const int* __restrict__ cnt,
                                                    int* __restrict__ rowptr,
                                                    int* __restrict__ bsum, int n) {
    __shared__ int sh[256];
    int b = blockIdx.x, t = threadIdx.x;
    int base = b * 1024 + t * 4;
    int v0 = base + 0 < n ? cnt[base + 0] : 0;
    int v1 = base + 1 < n ? cnt[base + 1] : 0;
    int v2 = base + 2 < n ? cnt[base + 2] : 0;
    int v3 = base + 3 < n ? cnt[base + 3] : 0;
    int tot = v0 + v1 + v2 + v3;
    sh[t] = tot;
    __syncthreads();
    for (int off = 1; off < 256; off <<= 1) {
        int x = (t >= off) ? sh[t - off] : 0;
        __syncthreads();
        sh[t] += x;
        __syncthreads();
    }
    int excl = (t > 0) ? sh[t - 1] : 0;
    if (base + 0 < n) rowptr[base + 0] = excl;
    if (base + 1 < n) rowptr[base + 1] = excl + v0;
    if (base + 2 < n) rowptr[base + 2] = excl + v0 + v1;
    if (base + 3 < n) rowptr[base + 3] = excl + v0 + v1 + v2;
    if (t == 255) bsum[b] = sh[255];
}

__global__ void k_scan_top(int* __restrict__ bsum, int* __restrict__ rowptr, int nb, int n) {
    if (threadIdx.x == 0 && blockIdx.x == 0) {
        int run = 0;
        for (int b = 0; b < nb; ++b) { int x = bsum[b]; bsum[b] = run; run += x; }
        rowptr[n] = run;
    }
}

__global__ void k_scan_add(int* __restrict__ rowptr, const int* __restrict__ bsum,
                           int* __restrict__ wptr, int n) {
    int i = blockIdx.x * blockDim.x + threadIdx.x;
    if (i < n) {
        int v = rowptr[i] + bsum[i >> 10];
        rowptr[i] = v;
        wptr[i] = v;
    }
}

// pack src (16 bits, N<65536) | flow<<16 into dst-sorted order
__global__ void k_scatter(const int* __restrict__ ei, const int* __restrict__ ea,
                          int* __restrict__ wptr, int* __restrict__ packed, int E) {
    int e = blockIdx.x * blockDim.x + threadIdx.x;
    if (e >= E) return;
    int s = ei[e], d = ei[E + e];
    int f = ea[2 * e];
    f = f < 0 ? 0 : (f > 2 ? 2 : f);
    int p = atomicAdd(&wptr[d], 1);
    packed[p] = (s & 0xFFFF) | (f << 16);
}

// ---------- GEMM 1: [N x 128] @ [128 x 256] for Wl and Wr, bf16 packed output ----------
// 32-node tile in LDS (broadcast reads). Thread = (mat, colpair): explicit 64 accs.
__global__ __launch_bounds__(256, 4) void k_gemm1(const int* __restrict__ x,
        const float* __restrict__ text_emb, const float* __restrict__ type_emb,
        const float* __restrict__ Wl, const float* __restrict__ bl,
        const float* __restrict__ Wr, const float* __restrict__ br,
        unsigned short* __restrict__ xlb, unsigned short* __restrict__ xrb, int n) {
    __shared__ float sh[32][128];
    int t = threadIdx.x;
    int node0 = blockIdx.x * 32;
    // stage h tile (embedding gather fused)
    for (int i = t; i < 32 * 128; i += 256) {
        int r = i >> 7, cc = i & 127;
        int nd = node0 + r;
        float v = 0.f;
        if (nd < n) {
            v = (cc < 64) ? text_emb[(size_t)x[nd * 2] * 64 + cc]
                          : type_emb[(size_t)x[nd * 2 + 1] * 64 + (cc - 64)];
        }
        sh[r][cc] = v;
    }
    __syncthreads();

    int m  = t >> 7;            // 0 -> Wl, 1 -> Wr
    int cp = t & 127;           // col pair index
    int c2 = cp * 2;
    const float* W = m ? Wr : Wl;
    float aA[32], aB[32];
#pragma unroll
    for (int nd = 0; nd < 32; ++nd) { aA[nd] = 0.f; aB[nd] = 0.f; }

#pragma unroll 1
    for (int kc = 0; kc < 128; kc += 16) {
        float2 w[16];
#pragma unroll
        for (int kk = 0; kk < 16; ++kk)
            w[kk] = *(const float2*)&W[(size_t)(kc + kk) * 256 + c2];
#pragma unroll
        for (int nd = 0; nd < 32; ++nd) {
#pragma unroll
            for (int kk = 0; kk < 16; kk += 4) {
                float4 hv = *(const float4*)&sh[nd][kc + kk];
                aA[nd] = fmaf(hv.x, w[kk + 0].x, aA[nd]);
                aB[nd] = fmaf(hv.x, w[kk + 0].y, aB[nd]);
                aA[nd] = fmaf(hv.y, w[kk + 1].x, aA[nd]);
                aB[nd] = fmaf(hv.y, w[kk + 1].y, aB[nd]);
                aA[nd] = fmaf(hv.z, w[kk + 2].x, aA[nd]);
                aB[nd] = fmaf(hv.z, w[kk + 2].y, aB[nd]);
                aA[nd] = fmaf(hv.w, w[kk + 3].x, aA[nd]);
                aB[nd] = fmaf(hv.w, w[kk + 3].y, aB[nd]);
            }
        }
    }
    float bA = m ? br[c2] : bl[c2];
    float bB = m ? br[c2 + 1] : bl[c2 + 1];
    unsigned short* dst = m ? xrb : xlb;
#pragma unroll
    for (int nd = 0; nd < 32; ++nd) {
        int node = node0 + nd;
        if (node < n)
            ((unsigned int*)(dst + (size_t)node * 256))[cp] = bf16pack(aA[nd] + bA, aB[nd] + bB);
    }
}

// ---------- GEMM 2: [N x 256] @ [256 x 32] for Wl and Wr, bf16 packed output ----------
// 32-node tile; thread = (mat, colpair, 4-node group)
__global__ __launch_bounds__(256, 4) void k_gemm2(const float* __restrict__ h2,
        const float* __restrict__ Wl, const float* __restrict__ bl,
        const float* __restrict__ Wr, const float* __restrict__ br,
        unsigned short* __restrict__ xlb, unsigned short* __restrict__ xrb, int n) {
    __shared__ float sh[32 * 260];  // pad 260 to break group bank aliasing
    int t = threadIdx.x;
    int node0 = blockIdx.x * 32;
    for (int i = t; i < 32 * 256; i += 256) {
        int r = i >> 8, cc = i & 255;
        int nd = node0 + r;
        sh[r * 260 + cc] = (nd < n) ? h2[(size_t)nd * 256 + cc] : 0.f;
    }
    __syncthreads();
    int combo = t >> 3;         // 0..31
    int g     = t & 7;          // node group: nodes g*4 .. g*4+3
    int m     = combo >> 4;     // matrix
    int cp    = combo & 15;     // col pair
    int c2    = cp * 2;
    const float* W = m ? Wr : Wl;
    float aA[4], aB[4];
#pragma unroll
    for (int nd = 0; nd < 4; ++nd) { aA[nd] = 0.f; aB[nd] = 0.f; }

#pragma unroll 1
    for (int kc = 0; kc < 256; kc += 16) {
        float2 w[16];
#pragma unroll
        for (int kk = 0; kk < 16; ++kk)
            w[kk] = *(const float2*)&W[(size_t)(kc + kk) * 32 + c2];
#pragma unroll
        for (int nd = 0; nd < 4; ++nd) {
            const float* row = &sh[(g * 4 + nd) * 260 + kc];
#pragma unroll
            for (int kk = 0; kk < 16; kk += 4) {
                float4 hv = *(const float4*)&row[kk];
                aA[nd] = fmaf(hv.x, w[kk + 0].x, aA[nd]);
                aB[nd] = fmaf(hv.x, w[kk + 0].y, aB[nd]);
                aA[nd] = fmaf(hv.y, w[kk + 1].x, aA[nd]);
                aB[nd] = fmaf(hv.y, w[kk + 1].y, aB[nd]);
                aA[nd] = fmaf(hv.z, w[kk + 2].x, aA[nd]);
                aB[nd] = fmaf(hv.z, w[kk + 2].y, aB[nd]);
                aA[nd] = fmaf(hv.w, w[kk + 3].x, aA[nd]);
                aB[nd] = fmaf(hv.w, w[kk + 3].y, aB[nd]);
            }
        }
    }
    float bA = m ? br[c2] : bl[c2];
    float bB = m ? br[c2 + 1] : bl[c2 + 1];
    unsigned short* dst = m ? xrb : xlb;
#pragma unroll
    for (int nd = 0; nd < 4; ++nd) {
        int node = node0 + g * 4 + nd;
        if (node < n)
            ((unsigned int*)(dst + (size_t)node * 32))[cp] = bf16pack(aA[nd] + bA, aB[nd] + bB);
    }
}

// ---------- GAT layer 1: one wave per dst, 4 edges in flight, bf16 gathers ----------
__global__ __launch_bounds__(256) void k_gat256(const unsigned short* __restrict__ xlb,
        const unsigned short* __restrict__ xrb, const int* __restrict__ rowptr,
        const int* __restrict__ packed, const float* __restrict__ eaW,
        const float* __restrict__ loopW, const float* __restrict__ att,
        const float* __restrict__ bias, float* __restrict__ out, int n) {
    int wid = (blockIdx.x * blockDim.x + threadIdx.x) >> 6;
    int lane = threadIdx.x & 63;
    if (wid >= n) return;
    int d = wid;
    int c = lane * 4;
    float4 xrd = bf16x4_to_f4(((const uint2*)(xrb + (size_t)d * 256))[lane]);
    float4 xld = bf16x4_to_f4(((const uint2*)(xlb + (size_t)d * 256))[lane]);
    float4 av  = *(const float4*)(att + c);
    // premixed per-flow vectors: r_f = xr[d] + eaW[f]
    float4 r0 = *(const float4*)(eaW + c);
    float4 r1 = *(const float4*)(eaW + 256 + c);
    float4 r2 = *(const float4*)(eaW + 512 + c);
    r0.x += xrd.x; r0.y += xrd.y; r0.z += xrd.z; r0.w += xrd.w;
    r1.x += xrd.x; r1.y += xrd.y; r1.z += xrd.z; r1.w += xrd.w;
    r2.x += xrd.x; r2.y += xrd.y; r2.z += xrd.z; r2.w += xrd.w;
    // self loop
    float4 lw = *(const float4*)(loopW + c);
    float4 sl; sl.x = xrd.x + lw.x; sl.y = xrd.y + lw.y;
    sl.z = xrd.z + lw.z; sl.w = xrd.w + lw.w;
    float q = wsum64(ldot4(xld, sl, av));
    float wself = __expf(q);
    float den = wself;
    float4 acc;
    acc.x = wself * xld.x; acc.y = wself * xld.y;
    acc.z = wself * xld.z; acc.w = wself * xld.w;

    int p0 = rowptr[d], p1 = rowptr[d + 1];
    int p = p0;
    for (; p + 4 <= p1; p += 4) {
        int pk0 = packed[p], pk1 = packed[p + 1];
        int pk2 = packed[p + 2], pk3 = packed[p + 3];
        uint2 u0 = ((const uint2*)(xlb + (size_t)(pk0 & 0xFFFF) * 256))[lane];
        uint2 u1 = ((const uint2*)(xlb + (size_t)(pk1 & 0xFFFF) * 256))[lane];
        uint2 u2 = ((const uint2*)(xlb + (size_t)(pk2 & 0xFFFF) * 256))[lane];
        uint2 u3 = ((const uint2*)(xlb + (size_t)(pk3 & 0xFFFF) * 256))[lane];
        float4 xs0 = bf16x4_to_f4(u0);
        float4 xs1 = bf16x4_to_f4(u1);
        float4 xs2 = bf16x4_to_f4(u2);
        float4 xs3 = bf16x4_to_f4(u3);
        int f0 = pk0 >> 16, f1 = pk1 >> 16, f2 = pk2 >> 16, f3 = pk3 >> 16;
        float4 pr0 = (f0 == 0) ? r0 : ((f0 == 1) ? r1 : r2);
        float4 pr1 = (f1 == 0) ? r0 : ((f1 == 1) ? r1 : r2);
        float4 pr2 = (f2 == 0) ? r0 : ((f2 == 1) ? r1 : r2);
        float4 pr3 = (f3 == 0) ? r0 : ((f3 == 1) ? r1 : r2);
        float q0 = ldot4(xs0, pr0, av);
        float q1 = ldot4(xs1, pr1, av);
        float q2 = ldot4(xs2, pr2, av);
        float q3 = ldot4(xs3, pr3, av);
#pragma unroll
        for (int off = 32; off >= 1; off >>= 1) {
            q0 += __shfl_xor(q0, off, 64);
            q1 += __shfl_xor(q1, off, 64);
            q2 += __shfl_xor(q2, off, 64);
            q3 += __shfl_xor(q3, off, 64);
        }
        float w0 = __expf(q0), w1 = __expf(q1);
        float w2 = __expf(q2), w3 = __expf(q3);
        den += (w0 + w1) + (w2 + w3);
        acc.x += w0 * xs0.x + w1 * xs1.x + w2 * xs2.x + w3 * xs3.x;
        acc.y += w0 * xs0.y + w1 * xs1.y + w2 * xs2.y + w3 * xs3.y;
        acc.z += w0 * xs0.z + w1 * xs1.z + w2 * xs2.z + w3 * xs3.z;
        acc.w += w0 * xs0.w + w1 * xs1.w + w2 * xs2.w + w3 * xs3.w;
    }
    for (; p < p1; ++p) {
        int pk = packed[p];
        float4 xs = bf16x4_to_f4(((const uint2*)(xlb + (size_t)(pk & 0xFFFF) * 256))[lane]);
        int f = pk >> 16;
        float4 pr = (f == 0) ? r0 : ((f == 1) ? r1 : r2);
        float qq = wsum64(ldot4(xs, pr, av));
        float w = __expf(qq);
        den += w;
        acc.x += w * xs.x; acc.y += w * xs.y; acc.z += w * xs.z; acc.w += w * xs.w;
    }
    float inv = 1.f / den;
    float4 bv = *(const float4*)(bias + c);
    float4 o;
    o.x = acc.x * inv + bv.x; o.y = acc.y * inv + bv.y;
    o.z = acc.z * inv + bv.z; o.w = acc.w * inv + bv.w;
    *(float4*)(out + (size_t)d * 256 + c) = o;
}

// ---------- GAT layer 2: one wave per dst, two half-wave edge streams, bf16 ----------
__global__ __launch_bounds__(256) void k_gat32(const unsigned short* __restrict__ xlb,
        const unsigned short* __restrict__ xrb, const int* __restrict__ rowptr,
        const int* __restrict__ packed, const float* __restrict__ eaW,
        const float* __restrict__ loopW, const float* __restrict__ att,
        const float* __restrict__ bias, float* __restrict__ out, int n) {
    int wid = (blockIdx.x * blockDim.x + threadIdx.x) >> 6;
    int lane = threadIdx.x & 63;
    if (wid >= n) return;
    int d = wid;
    int half = lane >> 5;
    int c = lane & 31;
    float xrd = __uint_as_float((unsigned int)xrb[(size_t)d * 32 + c] << 16);
    float xld = __uint_as_float((unsigned int)xlb[(size_t)d * 32 + c] << 16);
    float av = att[c];
    float r0 = eaW[c] + xrd, r1 = eaW[32 + c] + xrd, r2 = eaW[64 + c] + xrd;
    float den = 0.f, acc = 0.f;
    if (half == 0) {  // self loop counted once
        float lw = loopW[c];
        float q = wsum32(lrelu(xld + xrd + lw) * av);
        float wself = __expf(q);
        den = wself;
        acc = wself * xld;
    }
    int p0 = rowptr[d], p1 = rowptr[d + 1];
    int p = p0 + half;
    for (; p + 2 < p1; p += 4) {
        int pkA = packed[p], pkB = packed[p + 2];
        float xsA = __uint_as_float((unsigned int)xlb[(size_t)(pkA & 0xFFFF) * 32 + c] << 16);
        float xsB = __uint_as_float((unsigned int)xlb[(size_t)(pkB & 0xFFFF) * 32 + c] << 16);
        int fA = pkA >> 16, fB = pkB >> 16;
        float prA = (fA == 0) ? r0 : ((fA == 1) ? r1 : r2);
        float prB = (fB == 0) ? r0 : ((fB == 1) ? r1 : r2);
        float qA = lrelu(xsA + prA) * av;
        float qB = lrelu(xsB + prB) * av;
#pragma unroll
        for (int off = 16; off >= 1; off >>= 1) {
            qA += __shfl_xor(qA, off, 64);
            qB += __shfl_xor(qB, off, 64);
        }
        float wA = __expf(qA), wB = __expf(qB);
        den += wA + wB;
        acc += wA * xsA + wB * xsB;
    }
    for (; p < p1; p += 2) {
        int pk = packed[p];
        float xs = __uint_as_float((unsigned int)xlb[(size_t)(pk & 0xFFFF) * 32 + c] << 16);
        int f = pk >> 16;
        float pr = (f == 0) ? r0 : ((f == 1) ? r1 : r2);
        float q = wsum32(lrelu(xs + pr) * av);
        float w = __expf(q);
        den += w;
        acc += w * xs;
    }
    den += __shfl_xor(den, 32, 64);
    acc += __shfl_xor(acc, 32, 64);
    if (lane < 32) out[(size_t)d * 32 + c] = acc / den + bias[c];
}

// ---------- mean over nodes + policy head ----------
__global__ __launch_bounds__(256) void k_mean(const float* __restrict__ out2,
                                              float* __restrict__ gsum, int n) {
    __shared__ float sh[256];
    int t = threadIdx.x;
    int c = t & 31, g = t >> 5;
    float acc = 0.f;
    for (int nd = blockIdx.x * 8 + g; nd < n; nd += gridDim.x * 8)
        acc += out2[(size_t)nd * 32 + c];
    sh[t] = acc;
    __syncthreads();
    if (t < 32) {
        float s2 = 0.f;
#pragma unroll
        for (int gg = 0; gg < 8; ++gg) s2 += sh[gg * 32 + c];
        atomicAdd(&gsum[c], s2);
    }
}

__global__ void k_final(const float* __restrict__ gsum, const float* __restrict__ policy_W,
                        const float* __restrict__ policy_b, float* __restrict__ out, int n) {
    int t = threadIdx.x;  // 0..63 — one wave
    float invN = 1.0f / (float)n;
    float acc = policy_b[t];
    for (int cc = 0; cc < 32; ++cc) acc += gsum[cc] * invN * policy_W[cc * 64 + t];
    float mx = wmax64(acc);
    float ex = __expf(acc - mx);
    float s = wsum64(ex);
    out[t] = ex / s;
}

extern "C" void kernel_launch(void* const* d_in, const int* in_sizes, int n_in,
                              void* d_out, int out_size, void* d_ws, size_t ws_size,
                              hipStream_t stream) {
    const int* x          = (const int*)d_in[0];
    const int* edge_index = (const int*)d_in[1];
    const int* edge_attr  = (const int*)d_in[2];
    const float* text_emb = (const float*)d_in[3];
    const float* type_emb = (const float*)d_in[4];
    const float* flow_emb = (const float*)d_in[5];
    const float* pos_table= (const float*)d_in[6];
    const float* pos_W    = (const float*)d_in[7];
    const float* pos_b    = (const float*)d_in[8];
    const float* c1_Wl    = (const float*)d_in[9];
    const float* c1_bl    = (const float*)d_in[10];
    const float* c1_Wr    = (const float*)d_in[11];
    const float* c1_br    = (const float*)d_in[12];
    const float* c1_We    = (const float*)d_in[13];
    const float* c1_att   = (const float*)d_in[14];
    const float* c1_bias  = (const float*)d_in[15];
    const float* c2_Wl    = (const float*)d_in[16];
    const float* c2_bl    = (const float*)d_in[17];
    const float* c2_Wr    = (const float*)d_in[18];
    const float* c2_br    = (const float*)d_in[19];
    const float* c2_We    = (const float*)d_in[20];
    const float* c2_att   = (const float*)d_in[21];
    const float* c2_bias  = (const float*)d_in[22];
    const float* policy_W = (const float*)d_in[23];
    const float* policy_b = (const float*)d_in[24];
    float* out = (float*)d_out;

    const int N = in_sizes[0] / 2;   // 50000
    const int E = in_sizes[1] / 2;   // 800000

    // ---- workspace layout (256B-aligned chunks) ----
    char* base = (char*)d_ws;
    size_t off = 0;
    auto alloc = [&](size_t bytes) -> void* {
        void* p = base + off;
        off = (off + bytes + 255) & ~(size_t)255;
        return p;
    };
    unsigned short* xl1b = (unsigned short*)alloc((size_t)N * 256 * 2);
    unsigned short* xr1b = (unsigned short*)alloc((size_t)N * 256 * 2);
    float*          h2   = (float*)alloc((size_t)N * 256 * 4);
    unsigned short* xl2b = (unsigned short*)alloc((size_t)N * 32 * 2);
    unsigned short* xr2b = (unsigned short*)alloc((size_t)N * 32 * 2);
    float*          out2 = (float*)alloc((size_t)N * 32 * 4);
    int*            cntw   = (int*)alloc((size_t)N * 4);
    int*            rowptr = (int*)alloc((size_t)(N + 1) * 4);
    int*            packed = (int*)alloc((size_t)E * 4);
    int*            bsum   = (int*)alloc(64 * 4);
    int*            cnt3   = (int*)alloc(4 * 4);
    float*          eaW1   = (float*)alloc(768 * 4);
    float*          loopW1 = (float*)alloc(256 * 4);
    float*          eaW2   = (float*)alloc(96 * 4);
    float*          loopW2 = (float*)alloc(32 * 4);
    float*          gsum   = (float*)alloc(32 * 4);

    // ---- init (ws is poisoned 0xAA every call) ----
    k_zero_all<<<(N + 255) / 256, 256, 0, stream>>>(cntw, N, cnt3, (int*)gsum);

    // ---- fused histogram + flow counts ----
    k_edges<<<(E + 255) / 256, 256, 0, stream>>>(edge_index, edge_attr, cntw, cnt3, E);
    k_prep<<<1, 256, 0, stream>>>(pos_table, pos_W, pos_b, flow_emb, c1_We, c2_We,
                                  cnt3, eaW1, loopW1, eaW2, loopW2, E);

    // ---- CSR build (dst-sorted edge list) ----
    int nb = (N + 1023) / 1024;
    k_scan_block<<<nb, 256, 0, stream>>>(cntw, rowptr, bsum, N);
    k_scan_top<<<1, 64, 0, stream>>>(bsum, rowptr, nb, N);
    k_scan_add<<<(N + 255) / 256, 256, 0, stream>>>(rowptr, bsum, cntw, N);
    k_scatter<<<(E + 255) / 256, 256, 0, stream>>>(edge_index, edge_attr, cntw, packed, E);

    // ---- layer 1 ----
    k_gemm1<<<(N + 31) / 32, 256, 0, stream>>>(x, text_emb, type_emb,
                                               c1_Wl, c1_bl, c1_Wr, c1_br, xl1b, xr1b, N);
    k_gat256<<<(N + 3) / 4, 256, 0, stream>>>(xl1b, xr1b, rowptr, packed, eaW1, loopW1,
                                              c1_att, c1_bias, h2, N);

    // ---- layer 2 ----
    k_gemm2<<<(N + 31) / 32, 256, 0, stream>>>(h2, c2_Wl, c2_bl, c2_Wr, c2_br, xl2b, xr2b, N);
    k_gat32<<<(N + 3) / 4, 256, 0, stream>>>(xl2b, xr2b, rowptr, packed, eaW2, loopW2,
                                             c2_att, c2_bias, out2, N);

    // ---- readout ----
    k_mean<<<256, 256, 0, stream>>>(out2, gsum, N);
    k_final<<<1, 64, 0, stream>>>(gsum, policy_W, policy_b, out, N);
}

// Round 4
// 447.043 us; speedup vs baseline: 1.9332x; 1.9332x over previous
//
#include <hip/hip_runtime.h>

#define NEG_SLOPE 0.2f

typedef __attribute__((ext_vector_type(8))) short bf16x8;
typedef __attribute__((ext_vector_type(4))) float f32x4;

// leaky_relu(m) = 0.6*m + 0.4*|m| (exact for slope 0.2)
static __device__ __forceinline__ float lrelu(float m) {
    return fmaf(0.4f, fabsf(m), 0.6f * m);
}

static __device__ __forceinline__ float wsum64(float v) {
#pragma unroll
    for (int off = 32; off >= 1; off >>= 1) v += __shfl_xor(v, off, 64);
    return v;
}
static __device__ __forceinline__ float wsum32(float v) {
#pragma unroll
    for (int off = 16; off >= 1; off >>= 1) v += __shfl_xor(v, off, 64);
    return v;
}
static __device__ __forceinline__ float wmax64(float v) {
#pragma unroll
    for (int off = 32; off >= 1; off >>= 1) v = fmaxf(v, __shfl_xor(v, off, 64));
    return v;
}

// fp32 -> bf16 (RNE)
static __device__ __forceinline__ unsigned short bf16r(float a) {
    unsigned int u = __float_as_uint(a);
    return (unsigned short)((u + 0x7FFFu + ((u >> 16) & 1u)) >> 16);
}
// two fp32 -> packed bf16x2
static __device__ __forceinline__ unsigned int bf16pack(float a, float b) {
    unsigned int ua = __float_as_uint(a);
    ua = (ua + 0x7FFFu + ((ua >> 16) & 1u)) >> 16;
    unsigned int ub = __float_as_uint(b);
    ub = (ub + 0x7FFFu + ((ub >> 16) & 1u)) & 0xFFFF0000u;
    return ua | ub;
}
static __device__ __forceinline__ float bfld(unsigned short s) {
    return __uint_as_float((unsigned int)s << 16);
}
// expand 4 bf16 (uint2) -> float4
static __device__ __forceinline__ float4 bf16x4_to_f4(uint2 u) {
    float4 v;
    v.x = __uint_as_float(u.x << 16);
    v.y = __uint_as_float(u.x & 0xFFFF0000u);
    v.z = __uint_as_float(u.y << 16);
    v.w = __uint_as_float(u.y & 0xFFFF0000u);
    return v;
}

// per-lane partial of leakyrelu(xs + pre) . av over this lane's 4 dims
static __device__ __forceinline__ float ldot4(const float4 xs, const float4 pre,
                                              const float4 av) {
    float q;
    q  = lrelu(xs.x + pre.x) * av.x;
    q += lrelu(xs.y + pre.y) * av.y;
    q += lrelu(xs.z + pre.z) * av.z;
    q += lrelu(xs.w + pre.w) * av.w;
    return q;
}

// ---------- init ----------
__global__ void k_zero_all(int* __restrict__ cntw, int n, int* __restrict__ cnt3,
                           int* __restrict__ gsum) {
    int i = blockIdx.x * blockDim.x + threadIdx.x;
    if (i < n) cntw[i] = 0;
    if (i < 4) cnt3[i] = 0;
    if (i < 32) gsum[i] = 0;
}

// fused: dst histogram + flow-value counts
__global__ void k_edges(const int* __restrict__ ei, const int* __restrict__ ea,
                        int* __restrict__ cnt, int* __restrict__ cnt3, int E) {
    __shared__ int sh3[3];
    if (threadIdx.x < 3) sh3[threadIdx.x] = 0;
    __syncthreads();
    int e = blockIdx.x * blockDim.x + threadIdx.x;
    if (e < E) {
        atomicAdd(&cnt[ei[E + e]], 1);
        int f = ea[2 * e];
        f = f < 0 ? 0 : (f > 2 ? 2 : f);
        atomicAdd(&sh3[f], 1);
    }
    __syncthreads();
    if (threadIdx.x < 3) atomicAdd(&cnt3[threadIdx.x], sh3[threadIdx.x]);
}

// posc = pos_table[MAX_POS] @ pos_W + pos_b is constant for ALL edges
// (clip(where(pos>MP,pos,MP),0,MP) == MP identically). Project 3 flow vectors
// + self-loop mean vector through We1 / We2.
__global__ void k_prep(const float* __restrict__ pos_table, const float* __restrict__ pos_W,
                       const float* __restrict__ pos_b, const float* __restrict__ flow_emb,
                       const float* __restrict__ We1, const float* __restrict__ We2,
                       const int* __restrict__ cnt3,
                       float* __restrict__ eaW1, float* __restrict__ loopW1,
                       float* __restrict__ eaW2, float* __restrict__ loopW2, int E) {
    __shared__ float posc[128];
    __shared__ float lv[128];
    int t = threadIdx.x;
    if (t < 128) {
        const float* row = pos_table + 5120 * 128;
        float a = pos_b[t];
        for (int k = 0; k < 128; ++k) a += row[k] * pos_W[k * 128 + t];
        posc[t] = a;
        float invE = 1.0f / (float)E;
        lv[t] = ((float)cnt3[0] * flow_emb[t] + (float)cnt3[1] * flow_emb[128 + t] +
                 (float)cnt3[2] * flow_emb[256 + t]) * invE + a;
    }
    __syncthreads();
    {   // layer 1 projections, j = 0..255
        int j = t;
        float a0 = 0.f, a1 = 0.f, a2 = 0.f, al = 0.f;
        for (int k = 0; k < 128; ++k) {
            float w = We1[k * 256 + j];
            float pc = posc[k];
            a0 += (flow_emb[k] + pc) * w;
            a1 += (flow_emb[128 + k] + pc) * w;
            a2 += (flow_emb[256 + k] + pc) * w;
            al += lv[k] * w;
        }
        eaW1[j] = a0; eaW1[256 + j] = a1; eaW1[512 + j] = a2; loopW1[j] = al;
    }
    if (t < 32) {  // layer 2 projections
        int j = t;
        float a0 = 0.f, a1 = 0.f, a2 = 0.f, al = 0.f;
        for (int k = 0; k < 128; ++k) {
            float w = We2[k * 32 + j];
            float pc = posc[k];
            a0 += (flow_emb[k] + pc) * w;
            a1 += (flow_emb[128 + k] + pc) * w;
            a2 += (flow_emb[256 + k] + pc) * w;
            al += lv[k] * w;
        }
        eaW2[j] = a0; eaW2[32 + j] = a1; eaW2[64 + j] = a2; loopW2[j] = al;
    }
}

// bf16 n-major weight copies: Bt1[512][128] from c1_Wl|c1_Wr; Bt2[64][256] from c2_Wl|c2_Wr
__global__ void k_prepW(const float* __restrict__ Wl1, const float* __restrict__ Wr1,
                        const float* __restrict__ Wl2, const float* __restrict__ Wr2,
                        unsigned short* __restrict__ Bt1, unsigned short* __restrict__ Bt2) {
    int i = blockIdx.x * blockDim.x + threadIdx.x;
    if (i < 512 * 128) {
        int nn = i >> 7, k = i & 127;
        float v = (nn < 256) ? Wl1[(size_t)k * 256 + nn] : Wr1[(size_t)k * 256 + nn - 256];
        Bt1[i] = bf16r(v);
    } else {
        int j = i - 512 * 128;
        if (j < 64 * 256) {
            int nn = j >> 8, k = j & 255;
            float v = (nn < 32) ? Wl2[(size_t)k * 32 + nn] : Wr2[(size_t)k * 32 + nn - 32];
            Bt2[j] = bf16r(v);
        }
    }
}

// ---------- CSR-by-dst build ----------
__global__ __launch_bounds__(256) void k_scan_block(const int* __restrict__ cnt,
                                                    int* __restrict__ rowptr,
                                                    int* __restrict__ bsum, int n) {
    __shared__ int sh[256];
    int b = blockIdx.x, t = threadIdx.x;
    int base = b * 1024 + t * 4;
    int v0 = base + 0 < n ? cnt[base + 0] : 0;
    int v1 = base + 1 < n ? cnt[base + 1] : 0;
    int v2 = base + 2 < n ? cnt[base + 2] : 0;
    int v3 = base + 3 < n ? cnt[base + 3] : 0;
    int tot = v0 + v1 + v2 + v3;
    sh[t] = tot;
    __syncthreads();
    for (int off = 1; off < 256; off <<= 1) {
        int x = (t >= off) ? sh[t - off] : 0;
        __syncthreads();
        sh[t] += x;
        __syncthreads();
    }
    int excl = (t > 0) ? sh[t - 1] : 0;
    if (base + 0 < n) rowptr[base + 0] = excl;
    if (base + 1 < n) rowptr[base + 1] = excl + v0;
    if (base + 2 < n) rowptr[base + 2] = excl + v0 + v1;
    if (base + 3 < n) rowptr[base + 3] = excl + v0 + v1 + v2;
    if (t == 255) bsum[b] = sh[255];
}

__global__ void k_scan_top(int* __restrict__ bsum, int* __restrict__ rowptr, int nb, int n) {
    if (threadIdx.x == 0 && blockIdx.x == 0) {
        int run = 0;
        for (int b = 0; b < nb; ++b) { int x = bsum[b]; bsum[b] = run; run += x; }
        rowptr[n] = run;
    }
}

__global__ void k_scan_add(int* __restrict__ rowptr, const int* __restrict__ bsum,
                           int* __restrict__ wptr, int n) {
    int i = blockIdx.x * blockDim.x + threadIdx.x;
    if (i < n) {
        int v = rowptr[i] + bsum[i >> 10];
        rowptr[i] = v;
        wptr[i] = v;
    }
}

// pack src (16 bits, N<65536) | flow<<16 into dst-sorted order
__global__ void k_scatter(const int* __restrict__ ei, const int* __restrict__ ea,
                          int* __restrict__ wptr, int* __restrict__ packed, int E) {
    int e = blockIdx.x * blockDim.x + threadIdx.x;
    if (e >= E) return;
    int s = ei[e], d = ei[E + e];
    int f = ea[2 * e];
    f = f < 0 ? 0 : (f > 2 ? 2 : f);
    int p = atomicAdd(&wptr[d], 1);
    packed[p] = (s & 0xFFFF) | (f << 16);
}

// ---------- GEMM 1 (MFMA): xcat[N][512] = [h @ Wl+bl | h @ Wr+br], bf16 ----------
// A tile 64 nodes (embedding gather fused, fp32->bf16); loop 4 N-blocks of 128.
__global__ __launch_bounds__(256) void k_gemm1(const int* __restrict__ x,
        const float* __restrict__ text_emb, const float* __restrict__ type_emb,
        const unsigned short* __restrict__ Bt,  // [512][128] bf16, n-major
        const float* __restrict__ bl, const float* __restrict__ br,
        unsigned short* __restrict__ xc, int n) {
    __shared__ unsigned short Ash[64][136];   // pad 8 elems: 16B-aligned rows, 2-way banks
    __shared__ unsigned short Bsh[128][136];
    int t = threadIdx.x;
    int node0 = blockIdx.x * 64;
    for (int i = t; i < 64 * 128; i += 256) {
        int r = i >> 7, cc = i & 127;
        int nd = node0 + r;
        float v = 0.f;
        if (nd < n)
            v = (cc < 64) ? text_emb[(size_t)x[nd * 2] * 64 + cc]
                          : type_emb[(size_t)x[nd * 2 + 1] * 64 + (cc - 64)];
        Ash[r][cc] = bf16r(v);
    }
    int wave = t >> 6, lane = t & 63;
    int m = lane & 15, q = lane >> 4;
    for (int nb = 0; nb < 4; ++nb) {
        __syncthreads();   // also covers Ash on first iter; protects Bsh reuse after
        for (int i = t; i < 128 * 16; i += 256) {
            int r = i >> 4, cs = i & 15;
            uint4 v = ((const uint4*)(Bt + (size_t)(nb * 128 + r) * 128))[cs];
            *(uint4*)&Bsh[r][cs * 8] = v;
        }
        __syncthreads();
        f32x4 acc[8];
#pragma unroll
        for (int nt = 0; nt < 8; ++nt) acc[nt] = (f32x4){0.f, 0.f, 0.f, 0.f};
#pragma unroll
        for (int k = 0; k < 128; k += 32) {
            bf16x8 a = *(const bf16x8*)&Ash[wave * 16 + m][k + q * 8];
#pragma unroll
            for (int nt = 0; nt < 8; ++nt) {
                bf16x8 b = *(const bf16x8*)&Bsh[nt * 16 + m][k + q * 8];
                acc[nt] = __builtin_amdgcn_mfma_f32_16x16x32_bf16(a, b, acc[nt], 0, 0, 0);
            }
        }
        // C/D: col = lane&15, row = q*4 + reg
#pragma unroll
        for (int r = 0; r < 4; ++r) {
            int node = node0 + wave * 16 + q * 4 + r;
            if (node < n) {
                unsigned short* rowp = xc + (size_t)node * 512 + nb * 128 + m;
#pragma unroll
                for (int nt = 0; nt < 8; ++nt) {
                    int ng = nb * 128 + nt * 16 + m;
                    float bv = (ng < 256) ? bl[ng] : br[ng - 256];
                    rowp[nt * 16] = bf16r(acc[nt][r] + bv);
                }
            }
        }
    }
}

// ---------- GEMM 2 (MFMA): xcat2[N][64] = [h2 @ Wl+bl | h2 @ Wr+br], bf16 ----------
__global__ __launch_bounds__(256) void k_gemm2(const unsigned short* __restrict__ h2b,
        const unsigned short* __restrict__ Bt,  // [64][256] bf16, n-major
        const float* __restrict__ bl, const float* __restrict__ br,
        unsigned short* __restrict__ xc, int n) {
    __shared__ unsigned short Ash[32][264];
    __shared__ unsigned short Bsh[64][264];
    int t = threadIdx.x;
    int node0 = blockIdx.x * 32;
    for (int i = t; i < 32 * 32; i += 256) {
        int r = i >> 5, cs = i & 31;
        int nd = node0 + r;
        uint4 v = make_uint4(0u, 0u, 0u, 0u);
        if (nd < n) v = ((const uint4*)(h2b + (size_t)nd * 256))[cs];
        *(uint4*)&Ash[r][cs * 8] = v;
    }
    for (int i = t; i < 64 * 32; i += 256) {
        int r = i >> 5, cs = i & 31;
        uint4 v = ((const uint4*)(Bt + (size_t)r * 256))[cs];
        *(uint4*)&Bsh[r][cs * 8] = v;
    }
    __syncthreads();
    int wave = t >> 6, lane = t & 63;
    int m = lane & 15, q = lane >> 4;
    int mrow = (wave >> 1) * 16;
    int nh   = (wave & 1) * 32;
    f32x4 acc[2];
    acc[0] = (f32x4){0.f, 0.f, 0.f, 0.f};
    acc[1] = (f32x4){0.f, 0.f, 0.f, 0.f};
#pragma unroll
    for (int k = 0; k < 256; k += 32) {
        bf16x8 a = *(const bf16x8*)&Ash[mrow + m][k + q * 8];
#pragma unroll
        for (int nt = 0; nt < 2; ++nt) {
            bf16x8 b = *(const bf16x8*)&Bsh[nh + nt * 16 + m][k + q * 8];
            acc[nt] = __builtin_amdgcn_mfma_f32_16x16x32_bf16(a, b, acc[nt], 0, 0, 0);
        }
    }
#pragma unroll
    for (int r = 0; r < 4; ++r) {
        int node = node0 + mrow + q * 4 + r;
        if (node < n) {
#pragma unroll
            for (int nt = 0; nt < 2; ++nt) {
                int ng = nh + nt * 16 + m;
                float bv = (ng < 32) ? bl[ng] : br[ng - 32];
                xc[(size_t)node * 64 + ng] = bf16r(acc[nt][r] + bv);
            }
        }
    }
}

// ---------- GAT layer 1: one wave per dst, 4 edges in flight, bf16 in/out ----------
// xc1 rows: [node][0:256)=xl, [256:512)=xr
__global__ __launch_bounds__(256) void k_gat256(const unsigned short* __restrict__ xc1,
        const int* __restrict__ rowptr, const int* __restrict__ packed,
        const float* __restrict__ eaW, const float* __restrict__ loopW,
        const float* __restrict__ att, const float* __restrict__ bias,
        unsigned short* __restrict__ h2b, int n) {
    int wid = (blockIdx.x * blockDim.x + threadIdx.x) >> 6;
    int lane = threadIdx.x & 63;
    if (wid >= n) return;
    int d = wid;
    int c = lane * 4;
    float4 xld = bf16x4_to_f4(((const uint2*)(xc1 + (size_t)d * 512))[lane]);
    float4 xrd = bf16x4_to_f4(((const uint2*)(xc1 + (size_t)d * 512 + 256))[lane]);
    float4 av  = *(const float4*)(att + c);
    float4 r0 = *(const float4*)(eaW + c);
    float4 r1 = *(const float4*)(eaW + 256 + c);
    float4 r2 = *(const float4*)(eaW + 512 + c);
    r0.x += xrd.x; r0.y += xrd.y; r0.z += xrd.z; r0.w += xrd.w;
    r1.x += xrd.x; r1.y += xrd.y; r1.z += xrd.z; r1.w += xrd.w;
    r2.x += xrd.x; r2.y += xrd.y; r2.z += xrd.z; r2.w += xrd.w;
    float4 lw = *(const float4*)(loopW + c);
    float4 sl; sl.x = xrd.x + lw.x; sl.y = xrd.y + lw.y;
    sl.z = xrd.z + lw.z; sl.w = xrd.w + lw.w;
    float q = wsum64(ldot4(xld, sl, av));
    float wself = __expf(q);
    float den = wself;
    float4 acc;
    acc.x = wself * xld.x; acc.y = wself * xld.y;
    acc.z = wself * xld.z; acc.w = wself * xld.w;

    int p0 = rowptr[d], p1 = rowptr[d + 1];
    int p = p0;
    for (; p + 4 <= p1; p += 4) {
        int pk0 = packed[p], pk1 = packed[p + 1];
        int pk2 = packed[p + 2], pk3 = packed[p + 3];
        uint2 u0 = ((const uint2*)(xc1 + (size_t)(pk0 & 0xFFFF) * 512))[lane];
        uint2 u1 = ((const uint2*)(xc1 + (size_t)(pk1 & 0xFFFF) * 512))[lane];
        uint2 u2 = ((const uint2*)(xc1 + (size_t)(pk2 & 0xFFFF) * 512))[lane];
        uint2 u3 = ((const uint2*)(xc1 + (size_t)(pk3 & 0xFFFF) * 512))[lane];
        float4 xs0 = bf16x4_to_f4(u0);
        float4 xs1 = bf16x4_to_f4(u1);
        float4 xs2 = bf16x4_to_f4(u2);
        float4 xs3 = bf16x4_to_f4(u3);
        int f0 = pk0 >> 16, f1 = pk1 >> 16, f2 = pk2 >> 16, f3 = pk3 >> 16;
        float4 pr0 = (f0 == 0) ? r0 : ((f0 == 1) ? r1 : r2);
        float4 pr1 = (f1 == 0) ? r0 : ((f1 == 1) ? r1 : r2);
        float4 pr2 = (f2 == 0) ? r0 : ((f2 == 1) ? r1 : r2);
        float4 pr3 = (f3 == 0) ? r0 : ((f3 == 1) ? r1 : r2);
        float q0 = ldot4(xs0, pr0, av);
        float q1 = ldot4(xs1, pr1, av);
        float q2 = ldot4(xs2, pr2, av);
        float q3 = ldot4(xs3, pr3, av);
#pragma unroll
        for (int off = 32; off >= 1; off >>= 1) {
            q0 += __shfl_xor(q0, off, 64);
            q1 += __shfl_xor(q1, off, 64);
            q2 += __shfl_xor(q2, off, 64);
            q3 += __shfl_xor(q3, off, 64);
        }
        float w0 = __expf(q0), w1 = __expf(q1);
        float w2 = __expf(q2), w3 = __expf(q3);
        den += (w0 + w1) + (w2 + w3);
        acc.x += w0 * xs0.x + w1 * xs1.x + w2 * xs2.x + w3 * xs3.x;
        acc.y += w0 * xs0.y + w1 * xs1.y + w2 * xs2.y + w3 * xs3.y;
        acc.z += w0 * xs0.z + w1 * xs1.z + w2 * xs2.z + w3 * xs3.z;
        acc.w += w0 * xs0.w + w1 * xs1.w + w2 * xs2.w + w3 * xs3.w;
    }
    for (; p < p1; ++p) {
        int pk = packed[p];
        float4 xs = bf16x4_to_f4(((const uint2*)(xc1 + (size_t)(pk & 0xFFFF) * 512))[lane]);
        int f = pk >> 16;
        float4 pr = (f == 0) ? r0 : ((f == 1) ? r1 : r2);
        float qq = wsum64(ldot4(xs, pr, av));
        float w = __expf(qq);
        den += w;
        acc.x += w * xs.x; acc.y += w * xs.y; acc.z += w * xs.z; acc.w += w * xs.w;
    }
    float inv = 1.f / den;
    float4 bv = *(const float4*)(bias + c);
    float4 o;
    o.x = acc.x * inv + bv.x; o.y = acc.y * inv + bv.y;
    o.z = acc.z * inv + bv.z; o.w = acc.w * inv + bv.w;
    ((uint2*)(h2b + (size_t)d * 256))[lane] =
        make_uint2(bf16pack(o.x, o.y), bf16pack(o.z, o.w));
}

// ---------- GAT layer 2: one wave per dst, two half-wave edge streams ----------
// xc2 rows: [node][0:32)=xl, [32:64)=xr
__global__ __launch_bounds__(256) void k_gat32(const unsigned short* __restrict__ xc2,
        const int* __restrict__ rowptr, const int* __restrict__ packed,
        const float* __restrict__ eaW, const float* __restrict__ loopW,
        const float* __restrict__ att, const float* __restrict__ bias,
        float* __restrict__ out, int n) {
    int wid = (blockIdx.x * blockDim.x + threadIdx.x) >> 6;
    int lane = threadIdx.x & 63;
    if (wid >= n) return;
    int d = wid;
    int half = lane >> 5;
    int c = lane & 31;
    float xld = bfld(xc2[(size_t)d * 64 + c]);
    float xrd = bfld(xc2[(size_t)d * 64 + 32 + c]);
    float av = att[c];
    float r0 = eaW[c] + xrd, r1 = eaW[32 + c] + xrd, r2 = eaW[64 + c] + xrd;
    float den = 0.f, acc = 0.f;
    if (half == 0) {  // self loop counted once
        float lw = loopW[c];
        float q = wsum32(lrelu(xld + xrd + lw) * av);
        float wself = __expf(q);
        den = wself;
        acc = wself * xld;
    }
    int p0 = rowptr[d], p1 = rowptr[d + 1];
    int p = p0 + half;
    for (; p + 2 < p1; p += 4) {
        int pkA = packed[p], pkB = packed[p + 2];
        float xsA = bfld(xc2[(size_t)(pkA & 0xFFFF) * 64 + c]);
        float xsB = bfld(xc2[(size_t)(pkB & 0xFFFF) * 64 + c]);
        int fA = pkA >> 16, fB = pkB >> 16;
        float prA = (fA == 0) ? r0 : ((fA == 1) ? r1 : r2);
        float prB = (fB == 0) ? r0 : ((fB == 1) ? r1 : r2);
        float qA = lrelu(xsA + prA) * av;
        float qB = lrelu(xsB + prB) * av;
#pragma unroll
        for (int off = 16; off >= 1; off >>= 1) {
            qA += __shfl_xor(qA, off, 64);
            qB += __shfl_xor(qB, off, 64);
        }
        float wA = __expf(qA), wB = __expf(qB);
        den += wA + wB;
        acc += wA * xsA + wB * xsB;
    }
    for (; p < p1; p += 2) {
        int pk = packed[p];
        float xs = bfld(xc2[(size_t)(pk & 0xFFFF) * 64 + c]);
        int f = pk >> 16;
        float pr = (f == 0) ? r0 : ((f == 1) ? r1 : r2);
        float q = wsum32(lrelu(xs + pr) * av);
        float w = __expf(q);
        den += w;
        acc += w * xs;
    }
    den += __shfl_xor(den, 32, 64);
    acc += __shfl_xor(acc, 32, 64);
    if (lane < 32) out[(size_t)d * 32 + c] = acc / den + bias[c];
}

// ---------- mean over nodes + policy head ----------
__global__ __launch_bounds__(256) void k_mean(const float* __restrict__ out2,
                                              float* __restrict__ gsum, int n) {
    __shared__ float sh[256];
    int t = threadIdx.x;
    int c = t & 31, g = t >> 5;
    float acc = 0.f;
    for (int nd = blockIdx.x * 8 + g; nd < n; nd += gridDim.x * 8)
        acc += out2[(size_t)nd * 32 + c];
    sh[t] = acc;
    __syncthreads();
    if (t < 32) {
        float s2 = 0.f;
#pragma unroll
        for (int gg = 0; gg < 8; ++gg) s2 += sh[gg * 32 + c];
        atomicAdd(&gsum[c], s2);
    }
}

__global__ void k_final(const float* __restrict__ gsum, const float* __restrict__ policy_W,
                        const float* __restrict__ policy_b, float* __restrict__ out, int n) {
    int t = threadIdx.x;  // 0..63 — one wave
    float invN = 1.0f / (float)n;
    float acc = policy_b[t];
    for (int cc = 0; cc < 32; ++cc) acc += gsum[cc] * invN * policy_W[cc * 64 + t];
    float mx = wmax64(acc);
    float ex = __expf(acc - mx);
    float s = wsum64(ex);
    out[t] = ex / s;
}

extern "C" void kernel_launch(void* const* d_in, const int* in_sizes, int n_in,
                              void* d_out, int out_size, void* d_ws, size_t ws_size,
                              hipStream_t stream) {
    const int* x          = (const int*)d_in[0];
    const int* edge_index = (const int*)d_in[1];
    const int* edge_attr  = (const int*)d_in[2];
    const float* text_emb = (const float*)d_in[3];
    const float* type_emb = (const float*)d_in[4];
    const float* flow_emb = (const float*)d_in[5];
    const float* pos_table= (const float*)d_in[6];
    const float* pos_W    = (const float*)d_in[7];
    const float* pos_b    = (const float*)d_in[8];
    const float* c1_Wl    = (const float*)d_in[9];
    const float* c1_bl    = (const float*)d_in[10];
    const float* c1_Wr    = (const float*)d_in[11];
    const float* c1_br    = (const float*)d_in[12];
    const float* c1_We    = (const float*)d_in[13];
    const float* c1_att   = (const float*)d_in[14];
    const float* c1_bias  = (const float*)d_in[15];
    const float* c2_Wl    = (const float*)d_in[16];
    const float* c2_bl    = (const float*)d_in[17];
    const float* c2_Wr    = (const float*)d_in[18];
    const float* c2_br    = (const float*)d_in[19];
    const float* c2_We    = (const float*)d_in[20];
    const float* c2_att   = (const float*)d_in[21];
    const float* c2_bias  = (const float*)d_in[22];
    const float* policy_W = (const float*)d_in[23];
    const float* policy_b = (const float*)d_in[24];
    float* out = (float*)d_out;

    const int N = in_sizes[0] / 2;   // 50000
    const int E = in_sizes[1] / 2;   // 800000

    // ---- workspace layout (256B-aligned chunks) ----
    char* base = (char*)d_ws;
    size_t off = 0;
    auto alloc = [&](size_t bytes) -> void* {
        void* p = base + off;
        off = (off + bytes + 255) & ~(size_t)255;
        return p;
    };
    unsigned short* xc1  = (unsigned short*)alloc((size_t)N * 512 * 2);  // xl1|xr1 bf16
    unsigned short* h2b  = (unsigned short*)alloc((size_t)N * 256 * 2);  // h2 bf16
    unsigned short* xc2  = (unsigned short*)alloc((size_t)N * 64 * 2);   // xl2|xr2 bf16
    float*          out2 = (float*)alloc((size_t)N * 32 * 4);
    unsigned short* Bt1  = (unsigned short*)alloc((size_t)512 * 128 * 2);
    unsigned short* Bt2  = (unsigned short*)alloc((size_t)64 * 256 * 2);
    int*            cntw   = (int*)alloc((size_t)N * 4);
    int*            rowptr = (int*)alloc((size_t)(N + 1) * 4);
    int*            packed = (int*)alloc((size_t)E * 4);
    int*            bsum   = (int*)alloc(64 * 4);
    int*            cnt3   = (int*)alloc(4 * 4);
    float*          eaW1   = (float*)alloc(768 * 4);
    float*          loopW1 = (float*)alloc(256 * 4);
    float*          eaW2   = (float*)alloc(96 * 4);
    float*          loopW2 = (float*)alloc(32 * 4);
    float*          gsum   = (float*)alloc(32 * 4);

    // ---- init (ws is poisoned 0xAA every call) ----
    k_zero_all<<<(N + 255) / 256, 256, 0, stream>>>(cntw, N, cnt3, (int*)gsum);

    // ---- histogram + flow counts, constant projections, weight conversion ----
    k_edges<<<(E + 255) / 256, 256, 0, stream>>>(edge_index, edge_attr, cntw, cnt3, E);
    k_prep<<<1, 256, 0, stream>>>(pos_table, pos_W, pos_b, flow_emb, c1_We, c2_We,
                                  cnt3, eaW1, loopW1, eaW2, loopW2, E);
    k_prepW<<<(512 * 128 + 64 * 256 + 255) / 256, 256, 0, stream>>>(
        c1_Wl, c1_Wr, c2_Wl, c2_Wr, Bt1, Bt2);

    // ---- CSR build (dst-sorted edge list) ----
    int nb = (N + 1023) / 1024;
    k_scan_block<<<nb, 256, 0, stream>>>(cntw, rowptr, bsum, N);
    k_scan_top<<<1, 64, 0, stream>>>(bsum, rowptr, nb, N);
    k_scan_add<<<(N + 255) / 256, 256, 0, stream>>>(rowptr, bsum, cntw, N);
    k_scatter<<<(E + 255) / 256, 256, 0, stream>>>(edge_index, edge_attr, cntw, packed, E);

    // ---- layer 1 ----
    k_gemm1<<<(N + 63) / 64, 256, 0, stream>>>(x, text_emb, type_emb, Bt1,
                                               c1_bl, c1_br, xc1, N);
    k_gat256<<<(N + 3) / 4, 256, 0, stream>>>(xc1, rowptr, packed, eaW1, loopW1,
                                              c1_att, c1_bias, h2b, N);

    // ---- layer 2 ----
    k_gemm2<<<(N + 31) / 32, 256, 0, stream>>>(h2b, Bt2, c2_bl, c2_br, xc2, N);
    k_gat32<<<(N + 3) / 4, 256, 0, stream>>>(xc2, rowptr, packed, eaW2, loopW2,
                                             c2_att, c2_bias, out2, N);

    // ---- readout ----
    k_mean<<<256, 256, 0, stream>>>(out2, gsum, N);
    k_final<<<1, 64, 0, stream>>>(gsum, policy_W, policy_b, out, N);
}